// Round 5
// baseline (449.661 us; speedup 1.0000x reference)
//
#include <hip/hip_runtime.h>
#include <hip/hip_bf16.h>
#include <math.h>

#define B_   8
#define T_   2048
#define J_   17
#define D_   129
#define d_   128
#define H_   8
#define BJ_  (B_ * J_)      // 136
#define EPS_ 1e-6f

#define CHK  8
#define RPBK (T_ / CHK)     // 256 rows per block
#define NITK (RPBK / 64)    // 4
#define CHO  8
#define RPBO (T_ / CHO)     // 256 rows per block
#define NITO (RPBO / 64)    // 4

typedef short bf8 __attribute__((ext_vector_type(8)));   // 8 bf16 in 4 VGPRs
typedef float fx4 __attribute__((ext_vector_type(4)));
typedef const __attribute__((address_space(1))) unsigned char guc;
typedef __attribute__((address_space(3))) unsigned char luc;

__device__ __forceinline__ float phi_f(float x) {
    return x > 0.f ? x + 1.f : __expf(x);
}
// HW bf16 conversion (v_cvt_pk_bf16_f32) — never hand-roll the RNE.
__device__ __forceinline__ short f2b(float f) {
    __hip_bfloat16 h = __float2bfloat16(f);
    return *reinterpret_cast<short*>(&h);
}
__device__ __forceinline__ unsigned f2b2(float lo, float hi) {
    float2 p; p.x = lo; p.y = hi;
    __hip_bfloat162 h2 = __float22bfloat162_rn(p);
    return *reinterpret_cast<unsigned*>(&h2);
}
__device__ __forceinline__ float b2f(short s) {
    union { float f; unsigned u; } c;
    c.u = ((unsigned)(unsigned short)s) << 16;
    return c.f;
}
__device__ __forceinline__ bf8 ld_w8(const float* p) {   // 16B-aligned rows
    const float4* q = reinterpret_cast<const float4*>(p);
    float4 a = q[0], b = q[1];
    bf8 t;
    unsigned* tu = reinterpret_cast<unsigned*>(&t);
    tu[0] = f2b2(a.x, a.y); tu[1] = f2b2(a.z, a.w);
    tu[2] = f2b2(b.x, b.y); tu[3] = f2b2(b.z, b.w);
    return t;
}

// ============================================================================
// Pass A: k/v GEMM (cols 128..383) + kv[h] += k_m^T v + ksum, per bj.
// Identical to the 373µs round-4 kernel, plus: dump the bf16-swizzled sx tile
// to xbg (linear byte image, coalesced 16B stores) so pass_out can stage it
// with global_load_lds instead of re-reading fp32 x + converting.
// ============================================================================
__global__ __launch_bounds__(256) void pass_kv(
        const float* __restrict__ x,
        const float* __restrict__ wqkv, const float* __restrict__ bqkv,
        float* __restrict__ kvw,       // [BJ][H][16(j=v-feat)][16(i=k-feat)]
        float* __restrict__ ksw,       // [BJ][128]
        char* __restrict__ xbg,        // [BJ][32 tiles][16384 B] sx images
        const int packed) {
    const int bj = blockIdx.y, b = bj / J_, j = bj % J_;
    const int t0 = blockIdx.x * RPBK;
    const int tid = threadIdx.x, wave = tid >> 6, lane = tid & 63;
    const int quad = lane >> 4, l16 = lane & 15;
    const int rsw = (l16 & 7) << 4;                  // row-XOR for frag rows

    __shared__ __align__(16) short sx[64 * 128];     // 16384 B, swizzled
    __shared__ __align__(16) short kT[128 * 64];     // 16384 B, swizzled
    __shared__ __align__(16) short vT[128 * 64];     // 16384 B, swizzled

    bf8 wf[4][4];
    float bias[4];
    #pragma unroll
    for (int nt = 0; nt < 4; ++nt) {
        const int n = d_ + wave * 64 + nt * 16 + l16;
        bias[nt] = bqkv[n];
        #pragma unroll
        for (int ks = 0; ks < 4; ++ks)
            wf[nt][ks] = ld_w8(wqkv + (size_t)n * d_ + ks * 32 + quad * 8);
    }

    fx4 kva[2];
    kva[0] = (fx4){0.f, 0.f, 0.f, 0.f};
    kva[1] = (fx4){0.f, 0.f, 0.f, 0.f};
    float ksp[4] = {0.f, 0.f, 0.f, 0.f};

    for (int it = 0; it < NITK; ++it) {
        const int tb = t0 + it * 64;
        {   // stage x tile -> bf16 LDS (HW cvt_pk pairs)
            #pragma unroll
            for (int i = 0; i < 16; ++i) {
                const int F = tid + 256 * i, row = F >> 6, c2 = F & 63;
                const float* xr = x + ((size_t)((b * T_ + tb + row) * J_ + j)) * D_ + 1 + 2 * c2;
                *reinterpret_cast<unsigned*>(reinterpret_cast<char*>(sx) +
                    row * 256 + ((c2 * 4) ^ ((row & 7) << 4))) = f2b2(xr[0], xr[1]);
            }
        }
        __syncthreads();   // sx ready; also orders prev-iter kvMFMA vs kT/vT writes

        if (packed) {      // dump sx byte-image -> xbg (linear, coalesced)
            char* dst = xbg + ((size_t)(bj * 32) + (tb >> 6)) * 16384;
            const char* s = reinterpret_cast<const char*>(sx);
            #pragma unroll
            for (int u = 0; u < 4; ++u) {
                const int off = (tid + 256 * u) * 16;
                *reinterpret_cast<bf8*>(dst + off) =
                    *reinterpret_cast<const bf8*>(s + off);
            }
        }

        short* dst = (wave < 2) ? kT : vT;
        const int fbase = (wave & 1) * 64;
        const bool isk = (wave < 2);

        #pragma unroll
        for (int pr = 0; pr < 2; ++pr) {           // nt pair {2pr, 2pr+1}
            fx4 acc[2][4];
            #pragma unroll
            for (int n2 = 0; n2 < 2; ++n2)
                #pragma unroll
                for (int mt = 0; mt < 4; ++mt) acc[n2][mt] = (fx4){0.f, 0.f, 0.f, 0.f};

            #pragma unroll
            for (int ks = 0; ks < 4; ++ks) {
                bf8 af[4];
                #pragma unroll
                for (int mt = 0; mt < 4; ++mt)
                    af[mt] = *reinterpret_cast<const bf8*>(
                        reinterpret_cast<char*>(sx) + (mt * 16 + l16) * 256 +
                        ((ks * 64 + quad * 16) ^ rsw));
                #pragma unroll
                for (int n2 = 0; n2 < 2; ++n2)
                    #pragma unroll
                    for (int mt = 0; mt < 4; ++mt)
                        acc[n2][mt] = __builtin_amdgcn_mfma_f32_16x16x32_bf16(
                            af[mt], wf[pr * 2 + n2][ks], acc[n2][mt], 0, 0, 0);
            }

            // epilogue: bias (+phi for k), transpose-write to kT / vT (swizzled)
            #pragma unroll
            for (int n2 = 0; n2 < 2; ++n2) {
                const int nt = pr * 2 + n2;
                const int feat = fbase + nt * 16 + l16;    // feat&7 == l16&7
                #pragma unroll
                for (int mt = 0; mt < 4; ++mt) {
                    float v0 = acc[n2][mt][0] + bias[nt];
                    float v1 = acc[n2][mt][1] + bias[nt];
                    float v2 = acc[n2][mt][2] + bias[nt];
                    float v3 = acc[n2][mt][3] + bias[nt];
                    if (isk) {
                        v0 = phi_f(v0); v1 = phi_f(v1);
                        v2 = phi_f(v2); v3 = phi_f(v3);
                        ksp[nt] += (v0 + v1) + (v2 + v3);
                    }
                    const unsigned lo = f2b2(v0, v1), hi = f2b2(v2, v3);
                    *reinterpret_cast<unsigned long long*>(
                        reinterpret_cast<char*>(dst) + feat * 128 +
                        ((mt * 32 + quad * 8) ^ rsw)) =
                        (unsigned long long)lo | ((unsigned long long)hi << 32);
                }
            }
        }
        __syncthreads();   // kT/vT ready (cross-wave)

        // kv[h] += k_m^T(16 x 64t) * v(64t x 16): K = t, two 32-steps
        #pragma unroll
        for (int hh = 0; hh < 2; ++hh) {
            const int h = wave * 2 + hh;
            const int feat = h * 16 + l16;                 // feat&7 == l16&7
            #pragma unroll
            for (int ks2 = 0; ks2 < 2; ++ks2) {
                bf8 ak = *reinterpret_cast<const bf8*>(
                    reinterpret_cast<char*>(kT) + feat * 128 +
                    ((ks2 * 64 + quad * 16) ^ rsw));
                bf8 bv = *reinterpret_cast<const bf8*>(
                    reinterpret_cast<char*>(vT) + feat * 128 +
                    ((ks2 * 64 + quad * 16) ^ rsw));
                kva[hh] = __builtin_amdgcn_mfma_f32_16x16x32_bf16(ak, bv, kva[hh], 0, 0, 0);
            }
        }
    }

    #pragma unroll
    for (int hh = 0; hh < 2; ++hh) {
        const int h = wave * 2 + hh;
        float* p = kvw + (((size_t)bj * H_ + h) * 16 + l16) * 16 + quad * 4;
        #pragma unroll
        for (int r = 0; r < 4; ++r) atomicAdd(p + r, kva[hh][r]);
    }
    if (wave < 2) {
        #pragma unroll
        for (int nt = 0; nt < 4; ++nt) {
            float s = ksp[nt];
            s += __shfl_xor(s, 16);
            s += __shfl_xor(s, 32);
            if (lane < 16)
                atomicAdd(ksw + (size_t)bj * d_ + wave * 64 + nt * 16 + l16, s);
        }
    }
}

// ============================================================================
// Pass B: q GEMM -> phi -> [agg + denom via fused MFMA] -> out GEMM -> store.
// Round-4 logic; staging replaced by 4x global_load_lds(16B) from xbg (the
// byte-exact swizzled-tile image) — no VGPR round-trip, no cvt, no ds_write.
// ============================================================================
__global__ __launch_bounds__(256, 2) void pass_out(
        const float* __restrict__ x,
        const float* __restrict__ wqkv, const float* __restrict__ bqkv,
        const float* __restrict__ wout, const float* __restrict__ bout,
        const float* __restrict__ kvw, const float* __restrict__ ksw,
        const char* __restrict__ xbg, const int packed,
        float* __restrict__ out) {
    const int bj = blockIdx.y, b = bj / J_, j = bj % J_;
    const int t0 = blockIdx.x * RPBO;
    const int tid = threadIdx.x, wave = tid >> 6, lane = tid & 63;
    const int quad = lane >> 4, l16 = lane & 15;
    const int rsw = (l16 & 7) << 4;

    __shared__ __align__(16) short sxg[64 * 128];        // 16384 B, swizzled
    __shared__ __align__(16) short qm[64 * 136];         // q_m, then agg in-place
    __shared__ __align__(16) short kvT2[H_ * 2 * 16 * 8];// [h][qd][jv][8] (4096 B)
    __shared__ __align__(16) short ksshi[d_];
    __shared__ __align__(16) short ksslo[d_];
    __shared__ float rnorm[64];

    bf8 wqf[2][4], wof[2][4];
    float bq2[2], bo2[2];
    #pragma unroll
    for (int nt = 0; nt < 2; ++nt) {
        const int n = wave * 32 + nt * 16 + l16;
        bq2[nt] = bqkv[n];
        bo2[nt] = bout[n];
        #pragma unroll
        for (int ks = 0; ks < 4; ++ks) {
            wqf[nt][ks] = ld_w8(wqkv + (size_t)n * d_ + ks * 32 + quad * 8);
            wof[nt][ks] = ld_w8(wout + (size_t)n * d_ + ks * 32 + quad * 8);
        }
    }
    #pragma unroll
    for (int u = 0; u < 8; ++u) {
        const int lin = tid + 256 * u;                   // 0..2047
        const int jj = lin & 7, jv = (lin >> 3) & 15, qd = (lin >> 7) & 1, h = lin >> 8;
        kvT2[lin] = f2b(kvw[(((size_t)bj * H_ + h) * 16 + jv) * 16 + qd * 8 + jj]);
    }
    if (tid < d_) {                                      // ksum hi/lo split
        const float v = ksw[(size_t)bj * d_ + tid];
        const short hi = f2b(v);
        ksshi[tid] = hi;
        ksslo[tid] = f2b(v - b2f(hi));
    }
    if (tid < 64) rnorm[tid] = 0.f;

    for (int it = 0; it < NITO; ++it) {
        const int tb = t0 + it * 64;
        if (packed) {   // direct-to-LDS stage of the pre-swizzled bf16 image
            const char* gsrc = xbg + ((size_t)(bj * 32) + (tb >> 6)) * 16384
                             + (size_t)(wave * 4) * 1024 + (size_t)lane * 16;
            char* lbase = reinterpret_cast<char*>(sxg) + wave * 4096;
            #pragma unroll
            for (int c = 0; c < 4; ++c)
                __builtin_amdgcn_global_load_lds(
                    (guc*)(gsrc + c * 1024), (luc*)(lbase + c * 1024), 16, 0, 0);
        } else {        // fallback: fp32 x + HW cvt
            #pragma unroll
            for (int i = 0; i < 16; ++i) {
                const int F = tid + 256 * i, row = F >> 6, c2 = F & 63;
                const float* xr = x + ((size_t)((b * T_ + tb + row) * J_ + j)) * D_ + 1 + 2 * c2;
                *reinterpret_cast<unsigned*>(reinterpret_cast<char*>(sxg) +
                    row * 256 + ((c2 * 4) ^ ((row & 7) << 4))) = f2b2(xr[0], xr[1]);
            }
        }
        __syncthreads();   // (A) sxg ready (vmcnt drained); covers setup fills at it=0

        // q GEMM
        fx4 acc[2][4];
        #pragma unroll
        for (int nt = 0; nt < 2; ++nt)
            #pragma unroll
            for (int mt = 0; mt < 4; ++mt) acc[nt][mt] = (fx4){0.f, 0.f, 0.f, 0.f};
        #pragma unroll
        for (int ks = 0; ks < 4; ++ks) {
            bf8 af[4];
            #pragma unroll
            for (int mt = 0; mt < 4; ++mt)
                af[mt] = *reinterpret_cast<const bf8*>(
                    reinterpret_cast<char*>(sxg) + (mt * 16 + l16) * 256 +
                    ((ks * 64 + quad * 16) ^ rsw));
            #pragma unroll
            for (int nt = 0; nt < 2; ++nt)
                #pragma unroll
                for (int mt = 0; mt < 4; ++mt)
                    acc[nt][mt] = __builtin_amdgcn_mfma_f32_16x16x32_bf16(
                        af[mt], wqf[nt][ks], acc[nt][mt], 0, 0, 0);
        }
        // phi + write q_m to own column stripe (intra-wave producer/consumer)
        #pragma unroll
        for (int nt = 0; nt < 2; ++nt) {
            const int col = wave * 32 + nt * 16 + l16;
            #pragma unroll
            for (int mt = 0; mt < 4; ++mt)
                #pragma unroll
                for (int r = 0; r < 4; ++r)
                    qm[(mt * 16 + quad * 4 + r) * 136 + col] =
                        f2b(phi_f(acc[nt][mt][r] + bq2[nt]));
        }
        asm volatile("" ::: "memory");

        // agg = (q_m @ kv[h]) / denom; denom fused as 2 extra MFMAs.
        #pragma unroll
        for (int hh = 0; hh < 2; ++hh) {
            const int h = wave * 2 + hh;
            bf8 bk = (bf8){0, 0, 0, 0, 0, 0, 0, 0};
            bf8 bh = (bf8){0, 0, 0, 0, 0, 0, 0, 0};
            bf8 bl = (bf8){0, 0, 0, 0, 0, 0, 0, 0};
            if (quad < 2) {
                bk = *reinterpret_cast<const bf8*>(&kvT2[((h * 2 + quad) * 16 + l16) * 8]);
                bh = *reinterpret_cast<const bf8*>(&ksshi[h * 16 + quad * 8]);
                bl = *reinterpret_cast<const bf8*>(&ksslo[h * 16 + quad * 8]);
            }
            #pragma unroll
            for (int mt = 0; mt < 4; ++mt) {
                bf8 aq = (bf8){0, 0, 0, 0, 0, 0, 0, 0};
                if (quad < 2)
                    aq = *reinterpret_cast<const bf8*>(
                        &qm[(mt * 16 + l16) * 136 + h * 16 + quad * 8]);
                fx4 ag = __builtin_amdgcn_mfma_f32_16x16x32_bf16(
                    aq, bk, (fx4){0.f, 0.f, 0.f, 0.f}, 0, 0, 0);
                fx4 dd = __builtin_amdgcn_mfma_f32_16x16x32_bf16(
                    aq, bl, (fx4){0.f, 0.f, 0.f, 0.f}, 0, 0, 0);
                dd = __builtin_amdgcn_mfma_f32_16x16x32_bf16(aq, bh, dd, 0, 0, 0);
                #pragma unroll
                for (int r = 0; r < 4; ++r) {
                    const float rin = __builtin_amdgcn_rcpf(fmaxf(dd[r], EPS_));
                    qm[(mt * 16 + quad * 4 + r) * 136 + h * 16 + l16] =
                        f2b(ag[r] * rin);
                }
            }
        }
        __syncthreads();   // (B) agg (in qm) ready for cross-wave out GEMM

        // out GEMM + bias
        fx4 ya[2][4];
        #pragma unroll
        for (int nt = 0; nt < 2; ++nt)
            #pragma unroll
            for (int mt = 0; mt < 4; ++mt) ya[nt][mt] = (fx4){0.f, 0.f, 0.f, 0.f};
        #pragma unroll
        for (int ks = 0; ks < 4; ++ks) {
            bf8 af[4];
            #pragma unroll
            for (int mt = 0; mt < 4; ++mt)
                af[mt] = *reinterpret_cast<const bf8*>(
                    &qm[(mt * 16 + l16) * 136 + ks * 32 + quad * 8]);
            #pragma unroll
            for (int nt = 0; nt < 2; ++nt)
                #pragma unroll
                for (int mt = 0; mt < 4; ++mt)
                    ya[nt][mt] = __builtin_amdgcn_mfma_f32_16x16x32_bf16(
                        af[mt], wof[nt][ks], ya[nt][mt], 0, 0, 0);
        }

        // stores + row-norm
        #pragma unroll
        for (int mt = 0; mt < 4; ++mt) {
            float sq[4] = {0.f, 0.f, 0.f, 0.f};
            #pragma unroll
            for (int nt = 0; nt < 2; ++nt) {
                const int col = wave * 32 + nt * 16 + l16;
                #pragma unroll
                for (int r = 0; r < 4; ++r) {
                    const float y = ya[nt][mt][r] + bo2[nt];
                    const int t = tb + mt * 16 + quad * 4 + r;
                    out[((size_t)(b * T_ + t) * J_ + j) * D_ + 1 + col] = y;
                    sq[r] += y * y;
                }
            }
            #pragma unroll
            for (int r = 0; r < 4; ++r) {
                float s = sq[r];
                s += __shfl_xor(s, 1);
                s += __shfl_xor(s, 2);
                s += __shfl_xor(s, 4);
                s += __shfl_xor(s, 8);
                if (l16 == 0) atomicAdd(&rnorm[mt * 16 + quad * 4 + r], s);
            }
        }
        __syncthreads();   // (C) rnorm complete
        if (tid < 64) {
            const int t = tb + tid;
            out[((size_t)(b * T_ + t) * J_ + j) * D_] = sqrtf(1.f + rnorm[tid]);
            rnorm[tid] = 0.f;
        }
    }
}

extern "C" void kernel_launch(void* const* d_in, const int* in_sizes, int n_in,
                              void* d_out, int out_size, void* d_ws, size_t ws_size,
                              hipStream_t stream) {
    const float* x     = (const float*)d_in[0];
    const float* wqkv  = (const float*)d_in[1];
    const float* bqkv  = (const float*)d_in[2];
    const float* wout  = (const float*)d_in[3];
    const float* bout  = (const float*)d_in[4];
    float* out = (float*)d_out;

    float* kvw = (float*)d_ws;                          // BJ*H*16*16 fp32
    float* ksw = kvw + (size_t)BJ_ * H_ * 16 * 16;      // BJ*128 fp32
    const size_t zero_bytes =
        ((size_t)BJ_ * H_ * 16 * 16 + (size_t)BJ_ * d_) * sizeof(float);
    hipMemsetAsync(d_ws, 0, zero_bytes, stream);

    // bf16 swizzled-tile image of x (71.3 MB), produced by pass_kv's dump.
    char* xbg = (char*)d_ws + zero_bytes;               // 16B-aligned
    const size_t xbg_bytes = (size_t)BJ_ * 32 * 16384;
    const int packed = (ws_size >= zero_bytes + xbg_bytes) ? 1 : 0;

    dim3 blk(256);
    dim3 grdK(CHK, BJ_);
    dim3 grdO(CHO, BJ_);
    hipLaunchKernelGGL(pass_kv, grdK, blk, 0, stream, x, wqkv, bqkv, kvw, ksw,
                       xbg, packed);
    hipLaunchKernelGGL(pass_out, grdO, blk, 0, stream, x, wqkv, bqkv, wout, bout,
                       kvw, ksw, xbg, packed, out);
}

// Round 6
// 407.642 us; speedup vs baseline: 1.1031x; 1.1031x over previous
//
#include <hip/hip_runtime.h>
#include <hip/hip_bf16.h>
#include <math.h>

#define B_   8
#define T_   2048
#define J_   17
#define D_   129
#define d_   128
#define H_   8
#define BJ_  (B_ * J_)      // 136
#define EPS_ 1e-6f

#define CHK  8
#define RPBK (T_ / CHK)     // 256 rows per block
#define NITK (RPBK / 64)    // 4
#define CHO  8
#define RPBO (T_ / CHO)     // 256 rows per block
#define NITO (RPBO / 64)    // 4

typedef short bf8 __attribute__((ext_vector_type(8)));   // 8 bf16 in 4 VGPRs
typedef float fx4 __attribute__((ext_vector_type(4)));

__device__ __forceinline__ float phi_f(float x) {
    return x > 0.f ? x + 1.f : __expf(x);
}
// HW bf16 conversion (v_cvt_pk_bf16_f32) — never hand-roll the RNE.
__device__ __forceinline__ short f2b(float f) {
    __hip_bfloat16 h = __float2bfloat16(f);
    return *reinterpret_cast<short*>(&h);
}
__device__ __forceinline__ unsigned f2b2(float lo, float hi) {
    float2 p; p.x = lo; p.y = hi;
    __hip_bfloat162 h2 = __float22bfloat162_rn(p);
    return *reinterpret_cast<unsigned*>(&h2);
}
__device__ __forceinline__ float b2f(short s) {
    union { float f; unsigned u; } c;
    c.u = ((unsigned)(unsigned short)s) << 16;
    return c.f;
}
__device__ __forceinline__ bf8 ld_w8(const float* p) {   // 16B-aligned rows
    const float4* q = reinterpret_cast<const float4*>(p);
    float4 a = q[0], b = q[1];
    bf8 t;
    unsigned* tu = reinterpret_cast<unsigned*>(&t);
    tu[0] = f2b2(a.x, a.y); tu[1] = f2b2(a.z, a.w);
    tu[2] = f2b2(b.x, b.y); tu[3] = f2b2(b.z, b.w);
    return t;
}

// T14 async-STAGE split: issue 16x2 dword loads early (32 VGPR in flight),
// commit (cvt_pk + swizzled ds_write) late — HBM latency hides under MFMA.
__device__ __forceinline__ void x_issue(const float* __restrict__ x,
        int b, int j, int tb, int tid, float2* pf) {
    #pragma unroll
    for (int i = 0; i < 16; ++i) {
        const int F = tid + 256 * i, row = F >> 6, c2 = F & 63;
        const float* xr = x + ((size_t)((b * T_ + tb + row) * J_ + j)) * D_ + 1 + 2 * c2;
        float2 v; v.x = xr[0]; v.y = xr[1];   // 4B-aligned: two dword loads
        pf[i] = v;
    }
}
__device__ __forceinline__ void x_commit(short* sx, int tid, const float2* pf) {
    #pragma unroll
    for (int i = 0; i < 16; ++i) {
        const int F = tid + 256 * i, row = F >> 6, c2 = F & 63;
        *reinterpret_cast<unsigned*>(reinterpret_cast<char*>(sx) +
            row * 256 + ((c2 * 4) ^ ((row & 7) << 4))) = f2b2(pf[i].x, pf[i].y);
    }
}

// ============================================================================
// Pass A: k/v GEMM (cols 128..383) + kv[h] += k_m^T v + ksum, per bj.
// Round-4 (373µs) logic + async-stage split. 2 barriers/iter.
// sx commit for tile it+1 sits after the kv-MFMA; barrier A orders vs reads.
// ============================================================================
__global__ __launch_bounds__(256) void pass_kv(
        const float* __restrict__ x,
        const float* __restrict__ wqkv, const float* __restrict__ bqkv,
        float* __restrict__ kvw,       // [BJ][H][16(j=v-feat)][16(i=k-feat)]
        float* __restrict__ ksw) {     // [BJ][128]
    const int bj = blockIdx.y, b = bj / J_, j = bj % J_;
    const int t0 = blockIdx.x * RPBK;
    const int tid = threadIdx.x, wave = tid >> 6, lane = tid & 63;
    const int quad = lane >> 4, l16 = lane & 15;
    const int rsw = (l16 & 7) << 4;                  // row-XOR for frag rows

    __shared__ __align__(16) short sx[64 * 128];     // 16384 B, swizzled
    __shared__ __align__(16) short kT[128 * 64];     // 16384 B, swizzled
    __shared__ __align__(16) short vT[128 * 64];     // 16384 B, swizzled

    bf8 wf[4][4];
    float bias[4];
    #pragma unroll
    for (int nt = 0; nt < 4; ++nt) {
        const int n = d_ + wave * 64 + nt * 16 + l16;
        bias[nt] = bqkv[n];
        #pragma unroll
        for (int ks = 0; ks < 4; ++ks)
            wf[nt][ks] = ld_w8(wqkv + (size_t)n * d_ + ks * 32 + quad * 8);
    }

    fx4 kva[2];
    kva[0] = (fx4){0.f, 0.f, 0.f, 0.f};
    kva[1] = (fx4){0.f, 0.f, 0.f, 0.f};
    float ksp[4] = {0.f, 0.f, 0.f, 0.f};

    float2 pf[16];
    x_issue(x, b, j, t0, tid, pf);       // prologue: tile 0
    x_commit(sx, tid, pf);

    for (int it = 0; it < NITK; ++it) {
        __syncthreads();   // A: sx[it] ready; orders prev commit vs reads

        if (it + 1 < NITK)               // prefetch tile it+1 (in flight
            x_issue(x, b, j, t0 + (it + 1) * 64, tid, pf);   // during GEMM)

        short* dst = (wave < 2) ? kT : vT;
        const int fbase = (wave & 1) * 64;
        const bool isk = (wave < 2);

        #pragma unroll
        for (int pr = 0; pr < 2; ++pr) {           // nt pair {2pr, 2pr+1}
            fx4 acc[2][4];
            #pragma unroll
            for (int n2 = 0; n2 < 2; ++n2)
                #pragma unroll
                for (int mt = 0; mt < 4; ++mt) acc[n2][mt] = (fx4){0.f, 0.f, 0.f, 0.f};

            #pragma unroll
            for (int ks = 0; ks < 4; ++ks) {
                bf8 af[4];
                #pragma unroll
                for (int mt = 0; mt < 4; ++mt)
                    af[mt] = *reinterpret_cast<const bf8*>(
                        reinterpret_cast<char*>(sx) + (mt * 16 + l16) * 256 +
                        ((ks * 64 + quad * 16) ^ rsw));
                #pragma unroll
                for (int n2 = 0; n2 < 2; ++n2)
                    #pragma unroll
                    for (int mt = 0; mt < 4; ++mt)
                        acc[n2][mt] = __builtin_amdgcn_mfma_f32_16x16x32_bf16(
                            af[mt], wf[pr * 2 + n2][ks], acc[n2][mt], 0, 0, 0);
            }

            // epilogue: bias (+phi for k), transpose-write to kT / vT (swizzled)
            #pragma unroll
            for (int n2 = 0; n2 < 2; ++n2) {
                const int nt = pr * 2 + n2;
                const int feat = fbase + nt * 16 + l16;    // feat&7 == l16&7
                #pragma unroll
                for (int mt = 0; mt < 4; ++mt) {
                    float v0 = acc[n2][mt][0] + bias[nt];
                    float v1 = acc[n2][mt][1] + bias[nt];
                    float v2 = acc[n2][mt][2] + bias[nt];
                    float v3 = acc[n2][mt][3] + bias[nt];
                    if (isk) {
                        v0 = phi_f(v0); v1 = phi_f(v1);
                        v2 = phi_f(v2); v3 = phi_f(v3);
                        ksp[nt] += (v0 + v1) + (v2 + v3);
                    }
                    const unsigned lo = f2b2(v0, v1), hi = f2b2(v2, v3);
                    *reinterpret_cast<unsigned long long*>(
                        reinterpret_cast<char*>(dst) + feat * 128 +
                        ((mt * 32 + quad * 8) ^ rsw)) =
                        (unsigned long long)lo | ((unsigned long long)hi << 32);
                }
            }
        }
        __syncthreads();   // B: kT/vT ready (cross-wave); all sx reads done

        // kv[h] += k_m^T(16 x 64t) * v(64t x 16): K = t, two 32-steps
        #pragma unroll
        for (int hh = 0; hh < 2; ++hh) {
            const int h = wave * 2 + hh;
            const int feat = h * 16 + l16;                 // feat&7 == l16&7
            #pragma unroll
            for (int ks2 = 0; ks2 < 2; ++ks2) {
                bf8 ak = *reinterpret_cast<const bf8*>(
                    reinterpret_cast<char*>(kT) + feat * 128 +
                    ((ks2 * 64 + quad * 16) ^ rsw));
                bf8 bv = *reinterpret_cast<const bf8*>(
                    reinterpret_cast<char*>(vT) + feat * 128 +
                    ((ks2 * 64 + quad * 16) ^ rsw));
                kva[hh] = __builtin_amdgcn_mfma_f32_16x16x32_bf16(ak, bv, kva[hh], 0, 0, 0);
            }
        }

        if (it + 1 < NITK)               // commit tile it+1 (loads landed
            x_commit(sx, tid, pf);       // during GEMM; near-zero wait)
    }

    #pragma unroll
    for (int hh = 0; hh < 2; ++hh) {
        const int h = wave * 2 + hh;
        float* p = kvw + (((size_t)bj * H_ + h) * 16 + l16) * 16 + quad * 4;
        #pragma unroll
        for (int r = 0; r < 4; ++r) atomicAdd(p + r, kva[hh][r]);
    }
    if (wave < 2) {
        #pragma unroll
        for (int nt = 0; nt < 4; ++nt) {
            float s = ksp[nt];
            s += __shfl_xor(s, 16);
            s += __shfl_xor(s, 32);
            if (lane < 16)
                atomicAdd(ksw + (size_t)bj * d_ + wave * 64 + nt * 16 + l16, s);
        }
    }
}

// ============================================================================
// Pass B: q GEMM -> phi -> [agg + denom via fused MFMA] -> out GEMM -> store.
// Round-4 logic + async-stage split. 3 barriers/iter.
// No waves-per-EU bound: prefetch raises natural VGPR past the (256,2) cap.
// ============================================================================
__global__ __launch_bounds__(256) void pass_out(
        const float* __restrict__ x,
        const float* __restrict__ wqkv, const float* __restrict__ bqkv,
        const float* __restrict__ wout, const float* __restrict__ bout,
        const float* __restrict__ kvw, const float* __restrict__ ksw,
        float* __restrict__ out) {
    const int bj = blockIdx.y, b = bj / J_, j = bj % J_;
    const int t0 = blockIdx.x * RPBO;
    const int tid = threadIdx.x, wave = tid >> 6, lane = tid & 63;
    const int quad = lane >> 4, l16 = lane & 15;
    const int rsw = (l16 & 7) << 4;

    __shared__ __align__(16) short sxg[64 * 128];        // 16384 B, swizzled
    __shared__ __align__(16) short qm[64 * 136];         // q_m, then agg in-place
    __shared__ __align__(16) short kvT2[H_ * 2 * 16 * 8];// [h][qd][jv][8] (4096 B)
    __shared__ __align__(16) short ksshi[d_];
    __shared__ __align__(16) short ksslo[d_];
    __shared__ float rnorm[64];

    bf8 wqf[2][4], wof[2][4];
    float bq2[2], bo2[2];
    #pragma unroll
    for (int nt = 0; nt < 2; ++nt) {
        const int n = wave * 32 + nt * 16 + l16;
        bq2[nt] = bqkv[n];
        bo2[nt] = bout[n];
        #pragma unroll
        for (int ks = 0; ks < 4; ++ks) {
            wqf[nt][ks] = ld_w8(wqkv + (size_t)n * d_ + ks * 32 + quad * 8);
            wof[nt][ks] = ld_w8(wout + (size_t)n * d_ + ks * 32 + quad * 8);
        }
    }
    #pragma unroll
    for (int u = 0; u < 8; ++u) {
        const int lin = tid + 256 * u;                   // 0..2047
        const int jj = lin & 7, jv = (lin >> 3) & 15, qd = (lin >> 7) & 1, h = lin >> 8;
        kvT2[lin] = f2b(kvw[(((size_t)bj * H_ + h) * 16 + jv) * 16 + qd * 8 + jj]);
    }
    if (tid < d_) {                                      // ksum hi/lo split
        const float v = ksw[(size_t)bj * d_ + tid];
        const short hi = f2b(v);
        ksshi[tid] = hi;
        ksslo[tid] = f2b(v - b2f(hi));
    }
    if (tid < 64) rnorm[tid] = 0.f;

    float2 pf[16];
    x_issue(x, b, j, t0, tid, pf);       // prologue: tile 0
    x_commit(sxg, tid, pf);

    for (int it = 0; it < NITO; ++it) {
        const int tb = t0 + it * 64;
        __syncthreads();   // (A) sxg[it] ready; it=0 also covers setup fills

        if (it + 1 < NITO)               // prefetch next tile during qGEMM/agg
            x_issue(x, b, j, tb + 64, tid, pf);

        // q GEMM
        fx4 acc[2][4];
        #pragma unroll
        for (int nt = 0; nt < 2; ++nt)
            #pragma unroll
            for (int mt = 0; mt < 4; ++mt) acc[nt][mt] = (fx4){0.f, 0.f, 0.f, 0.f};
        #pragma unroll
        for (int ks = 0; ks < 4; ++ks) {
            bf8 af[4];
            #pragma unroll
            for (int mt = 0; mt < 4; ++mt)
                af[mt] = *reinterpret_cast<const bf8*>(
                    reinterpret_cast<char*>(sxg) + (mt * 16 + l16) * 256 +
                    ((ks * 64 + quad * 16) ^ rsw));
            #pragma unroll
            for (int nt = 0; nt < 2; ++nt)
                #pragma unroll
                for (int mt = 0; mt < 4; ++mt)
                    acc[nt][mt] = __builtin_amdgcn_mfma_f32_16x16x32_bf16(
                        af[mt], wqf[nt][ks], acc[nt][mt], 0, 0, 0);
        }
        // phi + write q_m to own column stripe (intra-wave producer/consumer)
        #pragma unroll
        for (int nt = 0; nt < 2; ++nt) {
            const int col = wave * 32 + nt * 16 + l16;
            #pragma unroll
            for (int mt = 0; mt < 4; ++mt)
                #pragma unroll
                for (int r = 0; r < 4; ++r)
                    qm[(mt * 16 + quad * 4 + r) * 136 + col] =
                        f2b(phi_f(acc[nt][mt][r] + bq2[nt]));
        }
        asm volatile("" ::: "memory");

        // agg = (q_m @ kv[h]) / denom; denom fused as 2 extra MFMAs.
        #pragma unroll
        for (int hh = 0; hh < 2; ++hh) {
            const int h = wave * 2 + hh;
            bf8 bk = (bf8){0, 0, 0, 0, 0, 0, 0, 0};
            bf8 bh = (bf8){0, 0, 0, 0, 0, 0, 0, 0};
            bf8 bl = (bf8){0, 0, 0, 0, 0, 0, 0, 0};
            if (quad < 2) {
                bk = *reinterpret_cast<const bf8*>(&kvT2[((h * 2 + quad) * 16 + l16) * 8]);
                bh = *reinterpret_cast<const bf8*>(&ksshi[h * 16 + quad * 8]);
                bl = *reinterpret_cast<const bf8*>(&ksslo[h * 16 + quad * 8]);
            }
            #pragma unroll
            for (int mt = 0; mt < 4; ++mt) {
                bf8 aq = (bf8){0, 0, 0, 0, 0, 0, 0, 0};
                if (quad < 2)
                    aq = *reinterpret_cast<const bf8*>(
                        &qm[(mt * 16 + l16) * 136 + h * 16 + quad * 8]);
                fx4 ag = __builtin_amdgcn_mfma_f32_16x16x32_bf16(
                    aq, bk, (fx4){0.f, 0.f, 0.f, 0.f}, 0, 0, 0);
                fx4 dd = __builtin_amdgcn_mfma_f32_16x16x32_bf16(
                    aq, bl, (fx4){0.f, 0.f, 0.f, 0.f}, 0, 0, 0);
                dd = __builtin_amdgcn_mfma_f32_16x16x32_bf16(aq, bh, dd, 0, 0, 0);
                #pragma unroll
                for (int r = 0; r < 4; ++r) {
                    const float rin = __builtin_amdgcn_rcpf(fmaxf(dd[r], EPS_));
                    qm[(mt * 16 + quad * 4 + r) * 136 + h * 16 + l16] =
                        f2b(ag[r] * rin);
                }
            }
        }
        __syncthreads();   // (B) agg (in qm) ready; all sxg reads done

        if (it + 1 < NITO)               // commit next tile (sxg dead after B;
            x_commit(sxg, tid, pf);      // loads landed during qGEMM/agg)

        // out GEMM + bias
        fx4 ya[2][4];
        #pragma unroll
        for (int nt = 0; nt < 2; ++nt)
            #pragma unroll
            for (int mt = 0; mt < 4; ++mt) ya[nt][mt] = (fx4){0.f, 0.f, 0.f, 0.f};
        #pragma unroll
        for (int ks = 0; ks < 4; ++ks) {
            bf8 af[4];
            #pragma unroll
            for (int mt = 0; mt < 4; ++mt)
                af[mt] = *reinterpret_cast<const bf8*>(
                    &qm[(mt * 16 + l16) * 136 + ks * 32 + quad * 8]);
            #pragma unroll
            for (int nt = 0; nt < 2; ++nt)
                #pragma unroll
                for (int mt = 0; mt < 4; ++mt)
                    ya[nt][mt] = __builtin_amdgcn_mfma_f32_16x16x32_bf16(
                        af[mt], wof[nt][ks], ya[nt][mt], 0, 0, 0);
        }

        // stores + row-norm
        #pragma unroll
        for (int mt = 0; mt < 4; ++mt) {
            float sq[4] = {0.f, 0.f, 0.f, 0.f};
            #pragma unroll
            for (int nt = 0; nt < 2; ++nt) {
                const int col = wave * 32 + nt * 16 + l16;
                #pragma unroll
                for (int r = 0; r < 4; ++r) {
                    const float y = ya[nt][mt][r] + bo2[nt];
                    const int t = tb + mt * 16 + quad * 4 + r;
                    out[((size_t)(b * T_ + t) * J_ + j) * D_ + 1 + col] = y;
                    sq[r] += y * y;
                }
            }
            #pragma unroll
            for (int r = 0; r < 4; ++r) {
                float s = sq[r];
                s += __shfl_xor(s, 1);
                s += __shfl_xor(s, 2);
                s += __shfl_xor(s, 4);
                s += __shfl_xor(s, 8);
                if (l16 == 0) atomicAdd(&rnorm[mt * 16 + quad * 4 + r], s);
            }
        }
        __syncthreads();   // (C) rnorm complete + sxg commit visible
        if (tid < 64) {
            const int t = tb + tid;
            out[((size_t)(b * T_ + t) * J_ + j) * D_] = sqrtf(1.f + rnorm[tid]);
            rnorm[tid] = 0.f;
        }
    }
}

extern "C" void kernel_launch(void* const* d_in, const int* in_sizes, int n_in,
                              void* d_out, int out_size, void* d_ws, size_t ws_size,
                              hipStream_t stream) {
    const float* x     = (const float*)d_in[0];
    const float* wqkv  = (const float*)d_in[1];
    const float* bqkv  = (const float*)d_in[2];
    const float* wout  = (const float*)d_in[3];
    const float* bout  = (const float*)d_in[4];
    float* out = (float*)d_out;

    float* kvw = (float*)d_ws;                          // BJ*H*16*16 fp32
    float* ksw = kvw + (size_t)BJ_ * H_ * 16 * 16;      // BJ*128 fp32
    const size_t zero_bytes =
        ((size_t)BJ_ * H_ * 16 * 16 + (size_t)BJ_ * d_) * sizeof(float);
    hipMemsetAsync(d_ws, 0, zero_bytes, stream);

    dim3 blk(256);
    dim3 grdK(CHK, BJ_);
    dim3 grdO(CHO, BJ_);
    hipLaunchKernelGGL(pass_kv, grdK, blk, 0, stream, x, wqkv, bqkv, kvw, ksw);
    hipLaunchKernelGGL(pass_out, grdO, blk, 0, stream, x, wqkv, bqkv, wout, bout,
                       kvw, ksw, out);
}